// Round 1
// 300.950 us; speedup vs baseline: 1.0224x; 1.0224x over previous
//
#include <hip/hip_runtime.h>
#include <cstdint>
#include <cstddef>

#define HH 128
#define SLOPE 0.01f

typedef __attribute__((ext_vector_type(8))) __bf16 bf16x8;
typedef __attribute__((ext_vector_type(8))) unsigned short ushort8v;
typedef __attribute__((ext_vector_type(4))) float f32x4;

__device__ __forceinline__ float lrelu(float x) { return x >= 0.f ? x : SLOPE * x; }
__device__ __forceinline__ unsigned short f2b(float f) {
  union { float f; unsigned u; } v; v.f = f;
  unsigned r = v.u + 0x7fffu + ((v.u >> 16) & 1u);  // round-to-nearest-even
  return (unsigned short)(r >> 16);
}
__device__ __forceinline__ float b2f(unsigned short u) {
  union { unsigned u; float f; } v; v.u = ((unsigned)u) << 16; return v.f;
}

// LDS tile layout with XOR swizzle: element (r,k) of a [rows]x128 bf16 tile lives at
// lofs(r,k). 16B chunks (8 ushorts) stay contiguous; chunk index ^= (r&15).
__device__ __forceinline__ int lofs(int r, int k) {
  return (r << 7) + ((((k >> 3) ^ r) & 15) << 3) + (k & 7);
}

// Single-wave LDS write->read sync: wave is lockstep (one PC), so ordering +
// lgkmcnt(0) drain is sufficient; no s_barrier, no vmcnt(0) drain.
#define WAVE_SYNC() asm volatile("s_waitcnt lgkmcnt(0)" ::: "memory")

// ---------------- CSR build ----------------

__global__ __launch_bounds__(256) void count_kernel(const int* __restrict__ dst,
                                                    int* __restrict__ cnt, int nE) {
  int e = blockIdx.x * 256 + threadIdx.x;
  if (e < nE) atomicAdd(&cnt[dst[e]], 1);
}

__global__ __launch_bounds__(1024) void scan1_kernel(int* __restrict__ cnt,
                                                     int* __restrict__ rowptr,
                                                     int* __restrict__ bsum,
                                                     float* __restrict__ dinv, int n) {
  __shared__ int wsum[16];
  const int tid = threadIdx.x;
  const int lane = tid & 63, wid = tid >> 6;
  int i = blockIdx.x * 1024 + tid;
  int v = (i < n) ? cnt[i] : 0;
  int x = v;
#pragma unroll
  for (int off = 1; off < 64; off <<= 1) {
    int y = __shfl_up(x, off, 64);
    if (lane >= off) x += y;
  }
  if (lane == 63) wsum[wid] = x;
  __syncthreads();
  if (tid == 0) {
    int s = 0;
#pragma unroll
    for (int w = 0; w < 16; ++w) { int t = wsum[w]; wsum[w] = s; s += t; }
    bsum[blockIdx.x] = s;
  }
  __syncthreads();
  if (i < n) {
    rowptr[i] = wsum[wid] + x - v;  // local exclusive
    dinv[i] = rsqrtf((float)v + 1.0f);
    cnt[i] = 0;
  }
}

__global__ __launch_bounds__(64) void scan2_kernel(int* __restrict__ bsum, int nb,
                                                   int* __restrict__ rowptr, int n, int E) {
  int lane = threadIdx.x;
  int v = (lane < nb) ? bsum[lane] : 0;
  int x = v;
#pragma unroll
  for (int off = 1; off < 64; off <<= 1) {
    int y = __shfl_up(x, off, 64);
    if (lane >= off) x += y;
  }
  if (lane < nb) bsum[lane] = x - v;  // exclusive
  if (lane == 0) rowptr[n] = E;
}

__global__ __launch_bounds__(1024) void scan3_kernel(int* __restrict__ rowptr,
                                                     const int* __restrict__ bsum, int n) {
  int i = blockIdx.x * 1024 + threadIdx.x;
  if (i < n) rowptr[i] += bsum[blockIdx.x];
}

// csr entry: .x = src node, .y = norm (float bits)
__global__ __launch_bounds__(256) void fill_kernel(const int* __restrict__ src,
                                                   const int* __restrict__ dst,
                                                   const int* __restrict__ rowptr,
                                                   int* __restrict__ cursor,
                                                   const float* __restrict__ dinv,
                                                   int2* __restrict__ csr, int nE) {
  int e = blockIdx.x * 256 + threadIdx.x;
  if (e >= nE) return;
  int d = dst[e], s = src[e];
  int pos = rowptr[d] + atomicAdd(&cursor[d], 1);
  int2 ent;
  ent.x = s;
  ent.y = __float_as_int(dinv[s] * dinv[d]);
  csr[pos] = ent;
}

// ---------------- weight pack: B-fragment order for mfma 16x16x32 ----------------
__global__ __launch_bounds__(256) void pack_kernel(const float* W0, const float* W1,
                                                   const float* W2, const float* W3,
                                                   const float* W4, const float* W5,
                                                   unsigned short* __restrict__ out) {
  const float* Ws[6] = {W0, W1, W2, W3, W4, W5};
  const float* W = Ws[blockIdx.y];
  int f = blockIdx.x * 256 + threadIdx.x;  // 0..16383
  int j = f & 7, L = (f >> 3) & 63, c = (f >> 9) & 7, t = f >> 12;
  int k = t * 32 + (L >> 4) * 8 + j;
  int n = c * 16 + (L & 15);
  out[(size_t)blockIdx.y * 16384 + f] = f2b(W[k * HH + n]);
}

// ---------------- shared device helpers ----------------

// A-fragments from a 16-row swizzled LDS tile; arow = lane&15.
__device__ __forceinline__ void mfma_stage(const unsigned short* __restrict__ Alds,
                                           const bf16x8* __restrict__ Wf,
                                           int arow, int lane, int quad, f32x4* acc) {
#pragma unroll
  for (int c = 0; c < 8; ++c) acc[c] = (f32x4){0.f, 0.f, 0.f, 0.f};
#pragma unroll
  for (int t = 0; t < 4; ++t) {
    bf16x8 a = *(const bf16x8*)&Alds[lofs(arow, t * 32 + quad * 8)];
#pragma unroll
    for (int c = 0; c < 8; ++c)
      acc[c] = __builtin_amdgcn_mfma_f32_16x16x32_bf16(a, Wf[(t * 8 + c) * 64 + lane], acc[c], 0, 0, 0);
  }
}

// ---------------- GEMM: A(fp32)[nrows,128] @ Wp -> bf16 out ----------------
// One wave per 16 rows, no LDS, no barriers: A fragments load straight from
// global fp32 (per-lane 32B contiguous; 128B/row segments across quads).

__global__ __launch_bounds__(64) void gemm_conv(const float* __restrict__ A,
                                                const unsigned short* __restrict__ Wp,
                                                unsigned short* __restrict__ out, int nrows) {
  const int lane = threadIdx.x;
  const int row0 = blockIdx.x * 16;
  const int m = lane & 15, quad = lane >> 4;
  const int gr = row0 + m;
  const bool rok = gr < nrows;
  const float* Arow = A + (size_t)gr * HH;
  const bf16x8* Wf = (const bf16x8*)Wp;

  bf16x8 af[4];
#pragma unroll
  for (int t = 0; t < 4; ++t) {
    const int k = t * 32 + quad * 8;
    float4 lo = make_float4(0.f, 0.f, 0.f, 0.f), hi = lo;
    if (rok) {
      lo = *(const float4*)(Arow + k);
      hi = *(const float4*)(Arow + k + 4);
    }
    union { ushort8v u; bf16x8 b; } cv;
    cv.u[0] = f2b(lo.x); cv.u[1] = f2b(lo.y); cv.u[2] = f2b(lo.z); cv.u[3] = f2b(lo.w);
    cv.u[4] = f2b(hi.x); cv.u[5] = f2b(hi.y); cv.u[6] = f2b(hi.z); cv.u[7] = f2b(hi.w);
    af[t] = cv.b;
  }

  f32x4 acc[8];
#pragma unroll
  for (int c = 0; c < 8; ++c) acc[c] = (f32x4){0.f, 0.f, 0.f, 0.f};
#pragma unroll
  for (int t = 0; t < 4; ++t)
#pragma unroll
    for (int c = 0; c < 8; ++c)
      acc[c] = __builtin_amdgcn_mfma_f32_16x16x32_bf16(af[t], Wf[(t * 8 + c) * 64 + lane], acc[c], 0, 0, 0);

#pragma unroll
  for (int c = 0; c < 8; ++c) {
    int col = c * 16 + m;
#pragma unroll
    for (int g = 0; g < 4; ++g) {
      int row = row0 + quad * 4 + g;
      if (row < nrows) out[(size_t)row * HH + col] = f2b(acc[c][g]);
    }
  }
}

// ---------------- agg: one wave per node ----------------
// out = leaky(sum norm*h[src] + self*dinv^2 + bias (+res fp32)); fp32 or bf16 out.

template <int RES, int OUTBF>
__global__ __launch_bounds__(256) void agg_kernel(const unsigned short* __restrict__ h,
                                                  const int* __restrict__ rowptr,
                                                  const int2* __restrict__ csr,
                                                  const float* __restrict__ dinv,
                                                  const float* __restrict__ bias,
                                                  const float* __restrict__ res,
                                                  void* __restrict__ outv, int n) {
  int node = blockIdx.x * 4 + (threadIdx.x >> 6);
  if (node >= n) return;
  int lane = threadIdx.x & 63;
  int c = lane << 1;
  int j = rowptr[node], end = rowptr[node + 1];
  float ax = 0.f, ay = 0.f;
  // 8-deep unroll: 8 outstanding gather loads per lane
  for (; j + 8 <= end; j += 8) {
    int2 e[8];
    ushort2 r[8];
#pragma unroll
    for (int q = 0; q < 8; ++q) e[q] = csr[j + q];
#pragma unroll
    for (int q = 0; q < 8; ++q) r[q] = *(const ushort2*)(h + (size_t)e[q].x * HH + c);
#pragma unroll
    for (int q = 0; q < 8; ++q) {
      float nv = __int_as_float(e[q].y);
      ax = fmaf(b2f(r[q].x), nv, ax); ay = fmaf(b2f(r[q].y), nv, ay);
    }
  }
  for (; j + 2 <= end; j += 2) {
    int2 e0 = csr[j], e1 = csr[j + 1];
    ushort2 r0 = *(const ushort2*)(h + (size_t)e0.x * HH + c);
    ushort2 r1 = *(const ushort2*)(h + (size_t)e1.x * HH + c);
    float n0 = __int_as_float(e0.y), n1 = __int_as_float(e1.y);
    ax = fmaf(b2f(r0.x), n0, ax); ay = fmaf(b2f(r0.y), n0, ay);
    ax = fmaf(b2f(r1.x), n1, ax); ay = fmaf(b2f(r1.y), n1, ay);
  }
  if (j < end) {
    int2 e0 = csr[j];
    float n0 = __int_as_float(e0.y);
    ushort2 r0 = *(const ushort2*)(h + (size_t)e0.x * HH + c);
    ax = fmaf(b2f(r0.x), n0, ax); ay = fmaf(b2f(r0.y), n0, ay);
  }
  float di = dinv[node], d2 = di * di;
  ushort2 hs = *(const ushort2*)(h + (size_t)node * HH + c);
  float2 b = *(const float2*)(bias + c);
  float ox = ax + b2f(hs.x) * d2 + b.x;
  float oy = ay + b2f(hs.y) * d2 + b.y;
  if (RES) {
    float2 r = *(const float2*)(res + (size_t)node * HH + c);
    ox += r.x; oy += r.y;
  }
  ox = lrelu(ox); oy = lrelu(oy);
  if (OUTBF) {
    ushort2 o; o.x = f2b(ox); o.y = f2b(oy);
    *(ushort2*)((unsigned short*)outv + (size_t)node * HH + c) = o;
  } else {
    *(float2*)((float*)outv + (size_t)node * HH + c) = make_float2(ox, oy);
  }
}

// ---------------- fusedMLP: 4 GEMM chain, one wave per 16 rows ----------------
// No __syncthreads: each 64-thread block is one wave owning an independent
// 16x128 tile; cross-lane LDS exchange uses WAVE_SYNC (lgkmcnt(0) + compiler
// memory fence). gen is consumed at fp32 directly into C-fragment registers.
// LDS = 2 x 4KB ping-pong (Al: f2 then p; Bl: m then q).
// stage 1:  m  = leaky(f2@Wm1+bm1)                         -> Bl
// stage 2:  h3 = leaky(m@Wm2+bm2 + f2); p = 0.5*(h3+gen)   -> Al
// stage 3:  q  = leaky(p@Wp1+bp1)                          -> Bl
// stage 4:  out= leaky(q@Wp2+bp2)                          -> fp32 global

__global__ __launch_bounds__(64) void fusedMLP(const unsigned short* __restrict__ f2bf,
                                               const unsigned short* __restrict__ Wm1p,
                                               const unsigned short* __restrict__ Wm2p,
                                               const unsigned short* __restrict__ Wp1p,
                                               const unsigned short* __restrict__ Wp2p,
                                               const float* __restrict__ bm1,
                                               const float* __restrict__ bm2,
                                               const float* __restrict__ bp1,
                                               const float* __restrict__ bp2,
                                               const float* __restrict__ gen,
                                               float* __restrict__ out, int n) {
  __shared__ __align__(16) unsigned short Al[16 * HH];
  __shared__ __align__(16) unsigned short Bl[16 * HH];
  const int lane = threadIdx.x;
  const int row0 = blockIdx.x * 16;
  const int m = lane & 15, quad = lane >> 4;

  // stage f2 tile (16x128 bf16 = 4KB) into Al, swizzled: 4 x 16B per lane
#pragma unroll
  for (int i = 0; i < 4; ++i) {
    int idx = i * 64 + lane;            // 16B-chunk id 0..255
    int r = idx >> 4, k = (idx & 15) << 3;
    int gr = row0 + r;
    ushort8v v = {0, 0, 0, 0, 0, 0, 0, 0};
    if (gr < n) v = *(const ushort8v*)(f2bf + (size_t)gr * HH + k);
    *(ushort8v*)&Al[lofs(r, k)] = v;
  }

  // gen preload, fp32, directly at C-fragment positions (held until stage 2;
  // HBM latency hides under stage 1)
  float genv[8][4];
#pragma unroll
  for (int cc = 0; cc < 8; ++cc)
#pragma unroll
    for (int g = 0; g < 4; ++g) {
      int grow = row0 + quad * 4 + g;
      genv[cc][g] = (grow < n) ? gen[(size_t)grow * HH + cc * 16 + m] : 0.f;
    }

  f32x4 acc[8];
  WAVE_SYNC();  // Al staged -> readable cross-lane

  // ---- stage 1 ----
  float b1v[8];
#pragma unroll
  for (int cc = 0; cc < 8; ++cc) b1v[cc] = bm1[cc * 16 + m];
  mfma_stage(Al, (const bf16x8*)Wm1p, m, lane, quad, acc);
#pragma unroll
  for (int cc = 0; cc < 8; ++cc) {
    int col = cc * 16 + m;
#pragma unroll
    for (int g = 0; g < 4; ++g) {
      int lrow = quad * 4 + g;
      Bl[lofs(lrow, col)] = f2b(lrelu(acc[cc][g] + b1v[cc]));
    }
  }
  WAVE_SYNC();

  // ---- stage 2 (residual from Al, interp with gen regs; p overwrites Al) ----
  float b2v[8];
#pragma unroll
  for (int cc = 0; cc < 8; ++cc) b2v[cc] = bm2[cc * 16 + m];
  mfma_stage(Bl, (const bf16x8*)Wm2p, m, lane, quad, acc);
#pragma unroll
  for (int cc = 0; cc < 8; ++cc) {
    int col = cc * 16 + m;
#pragma unroll
    for (int g = 0; g < 4; ++g) {
      int lrow = quad * 4 + g;
      float f2v = b2f(Al[lofs(lrow, col)]);   // same lane wrote/reads this slot
      float v = lrelu(acc[cc][g] + b2v[cc] + f2v);
      Al[lofs(lrow, col)] = f2b(0.5f * (v + genv[cc][g]));
    }
  }
  WAVE_SYNC();

  // ---- stage 3 ----
  float b3v[8];
#pragma unroll
  for (int cc = 0; cc < 8; ++cc) b3v[cc] = bp1[cc * 16 + m];
  mfma_stage(Al, (const bf16x8*)Wp1p, m, lane, quad, acc);
#pragma unroll
  for (int cc = 0; cc < 8; ++cc) {
    int col = cc * 16 + m;
#pragma unroll
    for (int g = 0; g < 4; ++g) {
      int lrow = quad * 4 + g;
      Bl[lofs(lrow, col)] = f2b(lrelu(acc[cc][g] + b3v[cc]));
    }
  }
  WAVE_SYNC();

  // ---- stage 4 ----
  float b4v[8];
#pragma unroll
  for (int cc = 0; cc < 8; ++cc) b4v[cc] = bp2[cc * 16 + m];
  mfma_stage(Bl, (const bf16x8*)Wp2p, m, lane, quad, acc);
#pragma unroll
  for (int cc = 0; cc < 8; ++cc) {
    int col = cc * 16 + m;
#pragma unroll
    for (int g = 0; g < 4; ++g) {
      int row = row0 + quad * 4 + g;
      if (row < n) out[(size_t)row * HH + col] = lrelu(acc[cc][g] + b4v[cc]);
    }
  }
}

// ---------------- launcher ----------------

extern "C" void kernel_launch(void* const* d_in, const int* in_sizes, int n_in,
                              void* d_out, int out_size, void* d_ws, size_t ws_size,
                              hipStream_t stream) {
  const float* x   = (const float*)d_in[0];
  const int* ei    = (const int*)d_in[1];
  const float* gen = (const float*)d_in[2];
  const float* Wc1 = (const float*)d_in[3];
  const float* bc1 = (const float*)d_in[4];
  const float* Wc2 = (const float*)d_in[5];
  const float* bc2 = (const float*)d_in[6];
  const float* Wm1 = (const float*)d_in[7];
  const float* bm1 = (const float*)d_in[8];
  const float* Wm2 = (const float*)d_in[9];
  const float* bm2 = (const float*)d_in[10];
  const float* Wp1 = (const float*)d_in[11];
  const float* bp1 = (const float*)d_in[12];
  const float* Wp2 = (const float*)d_in[13];
  const float* bp2 = (const float*)d_in[14];

  const int N = in_sizes[0] / HH;
  const int E = in_sizes[1] / 2;
  const int* src = ei;
  const int* dst = ei + E;

  char* ws = (char*)d_ws;
  size_t off = 0;
  auto alloc = [&](size_t bytes) { void* p = ws + off; off += (bytes + 255) & ~(size_t)255; return p; };
  float* dinv            = (float*)alloc((size_t)N * 4);
  int*   rowptr          = (int*)  alloc((size_t)(N + 1) * 4);
  int*   cursor          = (int*)  alloc((size_t)N * 4);
  int*   bsum            = (int*)  alloc((size_t)64 * 4);
  int2*  csr             = (int2*) alloc((size_t)E * 8);
  unsigned short* h_bf   = (unsigned short*)alloc((size_t)N * HH * 2);
  unsigned short* t2_bf  = (unsigned short*)alloc((size_t)N * HH * 2);
  unsigned short* f2_bf  = (unsigned short*)alloc((size_t)N * HH * 2);
  float* f1_f32          = (float*)alloc((size_t)N * HH * 4);
  unsigned short* packed = (unsigned short*)alloc((size_t)6 * 16384 * 2);
  float* fOut = (float*)d_out;

  const int wblocks = (N + 15) / 16;      // one wave (64 thr) per 16 rows
  const int eblocks = (E + 255) / 256;
  const int ablocks = (N + 3) / 4;
  const int sblocks = (N + 1023) / 1024;  // <= 64 for N <= 65536

  // weight packing
  pack_kernel<<<dim3(64, 6), 256, 0, stream>>>(Wc1, Wc2, Wm1, Wm2, Wp1, Wp2, packed);

  // CSR build
  hipMemsetAsync(cursor, 0, (size_t)N * 4, stream);
  count_kernel<<<eblocks, 256, 0, stream>>>(dst, cursor, E);
  scan1_kernel<<<sblocks, 1024, 0, stream>>>(cursor, rowptr, bsum, dinv, N);
  scan2_kernel<<<1, 64, 0, stream>>>(bsum, sblocks, rowptr, N, E);
  scan3_kernel<<<sblocks, 1024, 0, stream>>>(rowptr, bsum, N);
  fill_kernel<<<eblocks, 256, 0, stream>>>(src, dst, rowptr, cursor, dinv, csr, E);

  // conv1: h_bf = bf16(x @ Wc1)
  gemm_conv<<<wblocks, 64, 0, stream>>>(x, packed + 0 * 16384, h_bf, N);
  // agg1: f1 = leaky(agg(h_bf)+self+bc1)  [fp32]
  agg_kernel<0, 0><<<ablocks, 256, 0, stream>>>(h_bf, rowptr, csr, dinv, bc1, nullptr, f1_f32, N);
  // conv2: t2 = bf16(f1 @ Wc2)
  gemm_conv<<<wblocks, 64, 0, stream>>>(f1_f32, packed + 1 * 16384, t2_bf, N);
  // agg2: f2 = leaky(agg(t2)+self+bc2+f1)  [bf16 — only consumed as bf16]
  agg_kernel<1, 1><<<ablocks, 256, 0, stream>>>(t2_bf, rowptr, csr, dinv, bc2, f1_f32, f2_bf, N);
  // fusedMLP: MLP + interp + proj -> d_out
  fusedMLP<<<wblocks, 64, 0, stream>>>(f2_bf,
                                       packed + 2 * 16384, packed + 3 * 16384,
                                       packed + 4 * 16384, packed + 5 * 16384,
                                       bm1, bm2, bp1, bp2, gen, fOut, N);
}